// Round 6
// baseline (204.640 us; speedup 1.0000x reference)
//
#include <hip/hip_runtime.h>
#include <stdint.h>
#include <float.h>

#define TOTAL 16368
#define KSEL 500
#define CAP 1536
#define NSLOT 24          // CAP / 64
#define NBUCKET 64

// order-preserving float<->uint key (monotonic increasing on finite floats)
__device__ __forceinline__ uint32_t fkey(float f) {
    uint32_t u = __float_as_uint(f);
    return (u & 0x80000000u) ? ~u : (u | 0x80000000u);
}
__device__ __forceinline__ float keyf(uint32_t k) {
    uint32_t u = (k & 0x80000000u) ? (k & 0x7FFFFFFFu) : ~k;
    return __uint_as_float(u);
}

__device__ __forceinline__ int wave_sumi(int v) {
    #pragma unroll
    for (int o = 32; o > 0; o >>= 1) v += __shfl_xor(v, o, 64);
    return v;
}
__device__ __forceinline__ float wave_sumf(float v) {
    #pragma unroll
    for (int o = 32; o > 0; o >>= 1) v += __shfl_xor(v, o, 64);
    return v;
}
__device__ __forceinline__ float wave_maxf(float v) {
    #pragma unroll
    for (int o = 32; o > 0; o >>= 1) v = fmaxf(v, __shfl_xor(v, o, 64));
    return v;
}
__device__ __forceinline__ void lse_merge(float& m, float& l, float m2, float l2) {
    float M = fmaxf(m, m2);
    l = l * __expf(m - M) + l2 * __expf(m2 - M);
    m = M;
}

// async global->LDS DMA, 16B per lane: LDS dest = wave-uniform base + lane*16
__device__ __forceinline__ void dma16(const void* g, void* l) {
    __builtin_amdgcn_global_load_lds(
        (const __attribute__((address_space(1))) void*)g,
        (__attribute__((address_space(3))) void*)l, 16, 0, 0);
}

// exact exhaustive fallback (never taken for N(0,1) bench data); returns kl on
// lane 0 (0 elsewhere). Bisection on 45-bit key (fkey<<13 | (8191-idx)).
__device__ __noinline__ float wave_slow_kl(const float* __restrict__ t,
                                           const float* __restrict__ s, int C) {
    const int lane = threadIdx.x & 63;
    uint64_t lo = 0ull, hi = (1ull << 45), tau = 0ull;
    int cl = C, ch = 0;
    for (int it = 0; it < 100; ++it) {
        uint64_t span = hi - lo;
        if (span <= 1ull) { tau = lo; break; }
        uint64_t mid;
        if (it & 1) mid = lo + (span >> 1);
        else {
            uint64_t st = span * (uint64_t)(cl - KSEL) / (uint64_t)(cl - ch);
            if (st < 1) st = 1;
            if (st > span - 1) st = span - 1;
            mid = lo + st;
        }
        int c = 0;
        for (int i = lane; i < C; i += 64) {
            uint64_t ck = ((uint64_t)fkey(t[i]) << 13) | (uint64_t)(8191 - i);
            c += (ck > mid);
        }
        c = wave_sumi(c);
        if (c == KSEL) { tau = mid; break; }
        if (c > KSEL) { lo = mid; cl = c; } else { hi = mid; ch = c; }
    }
    float tmx = -FLT_MAX;
    for (int i = lane; i < C; i += 64) tmx = fmaxf(tmx, t[i]);
    tmx = wave_maxf(tmx);
    float St = 0.f, Stt = 0.f, Sts = 0.f, sm = -FLT_MAX;
    for (int i = lane; i < C; i += 64) {
        float x = t[i];
        uint64_t ck = ((uint64_t)fkey(x) << 13) | (uint64_t)(8191 - i);
        if (ck > tau) {
            float e = __expf(x - tmx), v = s[i];
            St += e; Stt += e * x; Sts += e * v;
            sm = fmaxf(sm, v);
        }
    }
    St = wave_sumf(St); Stt = wave_sumf(Stt); Sts = wave_sumf(Sts); sm = wave_maxf(sm);
    float Ss = 0.f;
    for (int i = lane; i < C; i += 64) {
        uint64_t ck = ((uint64_t)fkey(t[i]) << 13) | (uint64_t)(8191 - i);
        if (ck > tau) Ss += __expf(s[i] - sm);
    }
    Ss = wave_sumf(Ss);
    if (lane == 0)
        return (Stt - Sts) / St - tmx - __logf(St) + sm + __logf(Ss);
    return 0.f;
}

// Exact top-KSEL + KL on register-resident u32 keys (invalid slots key==0,
// real keys >= 0x00800000). Returns kl on lane 0 (0 elsewhere).
template <int NS, bool PREF, class IdxF>
__device__ float select_accum(uint32_t (&key)[NS], int nValid, IdxF idxOf,
                              const float* __restrict__ s) {
    const int lane = threadIdx.x & 63;
    float svp[NS];
    if (PREF) {  // dense groups: issue all student loads before the bisection
        #pragma unroll
        for (int j = 0; j < NS; ++j) svp[j] = s[idxOf(j)];
    }
    uint32_t kmx = 0u, kmn = 0xFFFFFFFFu;
    #pragma unroll
    for (int j = 0; j < NS; ++j) {
        uint32_t k = key[j];
        kmx = k > kmx ? k : kmx;
        if (k) kmn = k < kmn ? k : kmn;
    }
    #pragma unroll
    for (int o = 32; o > 0; o >>= 1) {
        uint32_t a = __shfl_xor(kmx, o, 64); kmx = a > kmx ? a : kmx;
        uint32_t b = __shfl_xor(kmn, o, 64); kmn = b < kmn ? b : kmn;
    }
    const float tmax = keyf(kmx);

    uint32_t tauhi; int cut;
    if (nValid == KSEL) { tauhi = kmn - 1u; cut = -1; }
    else {
        uint32_t lo = kmn - 1u, hi = kmx;
        int cl = nValid, ch = 0;
        bool exact = false;
        tauhi = hi; cut = -1;
        for (int it = 0; it < 80; ++it) {
            uint32_t span = hi - lo;
            if (span <= 1u) break;
            uint32_t mid;
            if (!(it & 1)) {  // false position on empirical CDF
                uint64_t st = (uint64_t)span * (uint32_t)(cl - KSEL) / (uint32_t)(cl - ch);
                if (st < 1) st = 1;
                if (st > span - 1) st = span - 1;
                mid = lo + (uint32_t)st;
            } else mid = lo + (span >> 1);
            int c = 0;
            #pragma unroll
            for (int j = 0; j < NS; ++j) c += (key[j] > mid);
            c = wave_sumi(c);
            if (c == KSEL) { tauhi = mid; cut = -1; exact = true; break; }
            if (c > KSEL) { lo = mid; cl = c; } else { hi = mid; ch = c; }
        }
        if (!exact) {
            tauhi = hi;
            const int nT = KSEL - ch, nTie = cl - ch;
            if (nT >= nTie) cut = 0x7FFFFFFF;
            else {  // lowest-index tie-break via index bisection (rare)
                int l = -1, h = 8191;
                while (h - l > 1) {
                    int m = (l + h) >> 1;
                    int c = 0;
                    #pragma unroll
                    for (int j = 0; j < NS; ++j)
                        c += (key[j] == tauhi && idxOf(j) <= m);
                    c = wave_sumi(c);
                    if (c >= nT) h = m; else l = m;
                }
                cut = h;
            }
        }
    }

    uint32_t selm = 0u;
    float sv[NS];
    #pragma unroll
    for (int j = 0; j < NS; ++j) {
        uint32_t kj = key[j];
        bool sj = (kj > tauhi) || (kj == tauhi && idxOf(j) <= cut);
        selm |= (sj ? 1u : 0u) << j;
        sv[j] = PREF ? svp[j] : (sj ? s[idxOf(j)] : 0.f);
    }
    float St = 0.f, Stt = 0.f, Sts = 0.f, sm = -FLT_MAX;
    #pragma unroll
    for (int j = 0; j < NS; ++j) {
        if (selm & (1u << j)) {
            float tv = keyf(key[j]);
            float e = __expf(tv - tmax);
            St += e; Stt += e * tv; Sts += e * sv[j];
            sm = fmaxf(sm, sv[j]);
        }
    }
    #pragma unroll
    for (int o = 32; o > 0; o >>= 1) {
        St  += __shfl_xor(St,  o, 64);
        Stt += __shfl_xor(Stt, o, 64);
        Sts += __shfl_xor(Sts, o, 64);
        sm = fmaxf(sm, __shfl_xor(sm, o, 64));
    }
    float Ss = 0.f;
    #pragma unroll
    for (int j = 0; j < NS; ++j)
        if (selm & (1u << j)) Ss += __expf(sv[j] - sm);
    Ss = wave_sumf(Ss);
    if (lane == 0)
        return (Stt - Sts) / St - tmax - __logf(St) + sm + __logf(Ss);
    return 0.f;
}

// big groups (C = NCH*256): DMA to LDS, compact > thr (vals overlaid on stage:
// writes < 6 KiB, chunk>=1 reads >= 8 KiB, chunk0 consumed before any write)
template <int NCH>
__device__ float big_wave(const float* __restrict__ tg, const float* __restrict__ s,
                          float thr, float* stageF, uint16_t* idxs) {
    const int lane = threadIdx.x & 63;
    #pragma unroll
    for (int c = 0; c < NCH; ++c)
        dma16((const char*)tg + c * 1024 + lane * 16, (char*)stageF + c * 1024);
    asm volatile("s_waitcnt vmcnt(0)" ::: "memory");

    const float4* st4 = (const float4*)stageF;
    float* vals = stageF;  // overlay
    const uint64_t ltm = (1ull << lane) - 1ull;
    int cnt = 0;
    #pragma unroll
    for (int c0 = 0; c0 < NCH * 64; c0 += 512) {   // 8 KiB super-chunks
        float4 buf[8];
        #pragma unroll
        for (int u = 0; u < 8; ++u) buf[u] = st4[c0 + u * 64 + lane];
        #pragma unroll
        for (int u = 0; u < 8; ++u) {
            float xs[4] = {buf[u].x, buf[u].y, buf[u].z, buf[u].w};
            #pragma unroll
            for (int q = 0; q < 4; ++q) {
                bool p = xs[q] > thr;
                uint64_t mb = __ballot(p);
                if (p) {
                    int pos = cnt + (int)__popcll(mb & ltm);
                    if (pos < CAP) {
                        vals[pos] = xs[q];
                        idxs[pos] = (uint16_t)(((c0 + u * 64 + lane) << 2) + q);
                    }
                }
                cnt += (int)__popcll(mb);
            }
        }
    }
    if (cnt < KSEL || cnt > CAP) return wave_slow_kl(tg, s, NCH * 256);
    uint32_t key[NSLOT], gidx[NSLOT];
    #pragma unroll
    for (int j = 0; j < NSLOT; ++j) {
        int p = lane + j * 64;
        bool v = p < cnt;
        key[j]  = v ? fkey(vals[p]) : 0u;
        gidx[j] = v ? (uint32_t)idxs[p] : 0u;
    }
    auto idxOf = [&](int j) { return (int)gidx[j]; };
    return select_accum<NSLOT, false>(key, cnt, idxOf, s);
}

// mid groups (C = NJ*64): keys straight to registers (t may be LDS or global)
template <int NJ>
__device__ float mid_wave(const float* __restrict__ t, const float* __restrict__ s) {
    const int lane = threadIdx.x & 63;
    const float4* t4 = (const float4*)t;
    uint32_t key[NJ];
    #pragma unroll
    for (int c = 0; c < NJ / 4; ++c) {
        float4 x = t4[lane + c * 64];
        key[4 * c + 0] = fkey(x.x); key[4 * c + 1] = fkey(x.y);
        key[4 * c + 2] = fkey(x.z); key[4 * c + 3] = fkey(x.w);
    }
    auto idxOf = [&](int j) { return ((lane + (j >> 2) * 64) << 2) + (j & 3); };
    return select_accum<NJ, true>(key, NJ * 64, idxOf, s);
}

// tiny groups (k == C): whole-group softmax; returns kl on lane 0
__device__ float tiny_group(const float* __restrict__ t, const float* __restrict__ s,
                            int Cg) {
    const int lane = threadIdx.x & 63;
    float St = 0.f, Stt = 0.f, Sts = 0.f, m = -FLT_MAX, l = 0.f;
    float tv[4], svv[4];
    #pragma unroll
    for (int q = 0; q < 4; ++q) {
        int i = lane + q * 64;
        bool va = i < Cg;
        tv[q] = va ? t[i] : -FLT_MAX;
        svv[q] = va ? s[i] : 0.f;
    }
    float mx = -FLT_MAX;
    #pragma unroll
    for (int q = 0; q < 4; ++q) mx = fmaxf(mx, tv[q]);
    mx = wave_maxf(mx);
    #pragma unroll
    for (int q = 0; q < 4; ++q) {
        if (lane + q * 64 < Cg) {
            float e = __expf(tv[q] - mx);
            St += e; Stt += e * tv[q]; Sts += e * svv[q];
            float x = svv[q];
            if (x > m) { l = l * __expf(m - x) + 1.f; m = x; }
            else       { l += __expf(x - m); }
        }
    }
    #pragma unroll
    for (int o = 32; o > 0; o >>= 1) {
        St  += __shfl_xor(St,  o, 64);
        Stt += __shfl_xor(Stt, o, 64);
        Sts += __shfl_xor(Sts, o, 64);
        float m2 = __shfl_xor(m, o, 64);
        float l2 = __shfl_xor(l, o, 64);
        lse_merge(m, l, m2, l2);
    }
    if (lane == 0)
        return (Stt - Sts) / St - mx - __logf(St) + m + __logf(l);
    return 0.f;
}

__global__ __launch_bounds__(64) void kd_all(const float* __restrict__ sL,
                                             const float* __restrict__ tL,
                                             float* __restrict__ res, int mode) {
    __shared__ float    stageF[8192];  // 32 KiB stage (vals overlaid)
    __shared__ uint16_t idxs[CAP];     // 3 KiB
    const int row = blockIdx.x;
    const int y = blockIdx.y;
    const float* tr = tL + (size_t)row * TOTAL;
    const float* sr = sL + (size_t)row * TOTAL;
    const int lane = threadIdx.x & 63;

    float kl = 0.f;
    switch (y) {
    case 0: kl = big_wave<32>(tr,        sr,        1.10f, stageF, idxs); break;
    case 1: kl = big_wave<16>(tr + 8192, sr + 8192, 0.60f, stageF, idxs); break;
    case 2: {
        #pragma unroll
        for (int c = 0; c < 12; ++c)
            dma16((const char*)(tr + 12288) + c * 1024 + lane * 16,
                  (char*)stageF + c * 1024);
        asm volatile("s_waitcnt vmcnt(0)" ::: "memory");
        kl  = mid_wave<32>(stageF,        sr + 12288);   // C=2048
        kl += mid_wave<16>(stageF + 2048, sr + 14336);   // C=1024
        break;
    }
    default:
        kl  = mid_wave<8>(tr + 15360, sr + 15360);       // C=512
        kl += tiny_group(tr + 15872, sr + 15872, 256);
        kl += tiny_group(tr + 16128, sr + 16128, 128);
        kl += tiny_group(tr + 16256, sr + 16256, 64);
        kl += tiny_group(tr + 16320, sr + 16320, 32);
        kl += tiny_group(tr + 16352, sr + 16352, 16);
        break;
    }
    if (lane == 0) {
        float v = kl * (0.1f / 1024.f);
        if (mode) res[row * 4 + y] = v;                       // slot mode: no atomics
        else atomicAdd(&res[(row + y * 37) & (NBUCKET - 1)], v);
    }
}

__global__ void zero_ws(float* partial) {
    if (threadIdx.x < NBUCKET) partial[threadIdx.x] = 0.f;
}

__global__ void final_sum(const float* __restrict__ partial, float* __restrict__ out,
                          int n) {
    __shared__ float scr[4];
    float v = 0.f;
    for (int i = threadIdx.x; i < n; i += 256) v += partial[i];
    #pragma unroll
    for (int o = 32; o > 0; o >>= 1) v += __shfl_down(v, o, 64);
    if ((threadIdx.x & 63) == 0) scr[threadIdx.x >> 6] = v;
    __syncthreads();
    if (threadIdx.x == 0) out[0] = scr[0] + scr[1] + scr[2] + scr[3];
}

extern "C" void kernel_launch(void* const* d_in, const int* in_sizes, int n_in,
                              void* d_out, int out_size, void* d_ws, size_t ws_size,
                              hipStream_t stream) {
    (void)in_sizes; (void)n_in; (void)out_size;
    const float* s = (const float*)d_in[0];
    const float* t = (const float*)d_in[1];
    float* out = (float*)d_out;
    float* ws = (float*)d_ws;

    const int mode = (ws_size >= 4096 * sizeof(float)) ? 1 : 0;
    if (!mode) hipLaunchKernelGGL(zero_ws, dim3(1), dim3(64), 0, stream, ws);
    hipLaunchKernelGGL(kd_all, dim3(1024, 4), dim3(64), 0, stream, s, t, ws, mode);
    hipLaunchKernelGGL(final_sum, dim3(1), dim3(256), 0, stream, ws, out,
                       mode ? 4096 : NBUCKET);
}